// Round 10
// baseline (172.674 us; speedup 1.0000x reference)
//
#include <hip/hip_runtime.h>

// ---------------------------------------------------------------------------
// Linear attention (causal, phi = elu+1), B=2 T=2048 H=16 dk=64 D=1024.
// r9 base (best: 164.7 us) + 128x64 GEMM tiles: 2x block count (gemm_qkv
// ~6 blocks/CU, gemm_out 2/CU) so barrier drains overlap across co-resident
// blocks (m114 wave-level overlap). r8/r3 attribution showed the r3 retile
// was actually a ~4us win masked by the +8.7us prefix-fold regression.
// ---------------------------------------------------------------------------

typedef float  f32x4   __attribute__((ext_vector_type(4)));
typedef __bf16 bf16x8  __attribute__((ext_vector_type(8)));
typedef short  short8v __attribute__((ext_vector_type(8)));
typedef short  short4v __attribute__((ext_vector_type(4)));

static __device__ __forceinline__ short f2bf(float f) {
    unsigned u = __float_as_uint(f);
    u += 0x7FFFu + ((u >> 16) & 1u);          // RNE
    return (short)(u >> 16);
}
static __device__ __forceinline__ float bf2f(short s) {
    return __uint_as_float(((unsigned)(unsigned short)s) << 16);
}
static __device__ __forceinline__ float phi(float x) {   // elu(x)+1
    return x > 0.f ? x + 1.f : __expf(x);
}
static __device__ __forceinline__ void gl_lds16(const short* g, short* l) {
    __builtin_amdgcn_global_load_lds(
        (const __attribute__((address_space(1))) void*)g,
        (__attribute__((address_space(3))) void*)l, 16, 0, 0);
}

#define LDT 72   // 64x64 tile leading dim
static __device__ __forceinline__ int swz(int row, int col) {
    return row * LDT + (col ^ (row & 56));
}

// ---------------- Kernel 0: fp32 -> bf16 conversion ------------------------
__global__ __launch_bounds__(256) void convert_bf16(
    const float* __restrict__ x,  const float* __restrict__ Wq,
    const float* __restrict__ Wk, const float* __restrict__ Wv,
    const float* __restrict__ Wo,
    short* __restrict__ xb,  short* __restrict__ Wqb,
    short* __restrict__ Wkb, short* __restrict__ Wvb, short* __restrict__ Wob)
{
    const int blk = blockIdx.x;
    const float* src; short* dst; size_t base;
    if (blk < 2048)      { src = x;  dst = xb;  base = (size_t)blk * 2048; }
    else if (blk < 2560) { src = Wq; dst = Wqb; base = (size_t)(blk - 2048) * 2048; }
    else if (blk < 3072) { src = Wk; dst = Wkb; base = (size_t)(blk - 2560) * 2048; }
    else if (blk < 3584) { src = Wv; dst = Wvb; base = (size_t)(blk - 3072) * 2048; }
    else                 { src = Wo; dst = Wob; base = (size_t)(blk - 3584) * 2048; }
    const size_t o = base + (size_t)threadIdx.x * 8;
    f32x4 v0 = *(const f32x4*)&src[o];
    f32x4 v1 = *(const f32x4*)&src[o + 4];
    short8v s;
#pragma unroll
    for (int m = 0; m < 4; ++m) { s[m] = f2bf(v0[m]); s[m + 4] = f2bf(v1[m]); }
    *(short8v*)&dst[o] = s;
}

// ---------------- Kernel 1: fused QKV GEMM, 128x64 tile --------------------
// Grid 32 x 48 = 1536 blocks (~6/CU). Output [(b*16+h)*2048 + t][64] bf16.
// Each block covers exactly one head (64 W-rows).
__global__ __launch_bounds__(256) void gemm_qkv(
    const short* __restrict__ xb,
    const short* __restrict__ Wqb, const short* __restrict__ Wkb,
    const short* __restrict__ Wvb,
    const float* __restrict__ bq, const float* __restrict__ bk,
    const float* __restrict__ bv,
    short* __restrict__ Qb, short* __restrict__ Kb, short* __restrict__ Vb)
{
    __shared__ short As[128 * 32];
    __shared__ short Bs[64 * 32];
    const int tid = threadIdx.x;
    const int bm = blockIdx.x, bn = blockIdx.y;      // 32 x 48
    const int wsel = bn >> 4;                        // 0=Q 1=K 2=V
    const int n0 = (bn & 15) << 6;                   // 64 W-rows = one head
    const short* __restrict__ W    = (wsel == 0) ? Wqb : (wsel == 1) ? Wkb : Wvb;
    const float* __restrict__ bias = (wsel == 0) ? bq  : (wsel == 1) ? bk  : bv;
    short* __restrict__ Ob         = (wsel == 0) ? Qb  : (wsel == 1) ? Kb  : Vb;
    const int m0 = bm << 7;
    const int wave = tid >> 6, lane = tid & 63;
    const int wm = (wave & 1) << 6, wn = (wave >> 1) << 5;
    const int l15 = lane & 15, quad = lane >> 4;

    // 12 staging chunks (8 A + 4 B), wave w owns chunks 3w..3w+2
    const int lrow = lane >> 2, lcol = (lane & 3) << 3;
    const short* gp[3]; short* lp[3];
#pragma unroll
    for (int cc = 0; cc < 3; ++cc) {
        const int ch = wave * 3 + cc;
        if (ch < 8) {
            gp[cc] = xb + (size_t)(m0 + ch * 16 + lrow) * 1024 + lcol;
            lp[cc] = &As[ch * 512];
        } else {
            gp[cc] = W + (size_t)(n0 + (ch - 8) * 16 + lrow) * 1024 + lcol;
            lp[cc] = &Bs[(ch - 8) * 512];
        }
    }

    f32x4 acc[4][2] = {};
    for (int k0 = 0; k0 < 1024; k0 += 32) {
        __syncthreads();
        gl_lds16(gp[0] + k0, lp[0]);
        gl_lds16(gp[1] + k0, lp[1]);
        gl_lds16(gp[2] + k0, lp[2]);
        __syncthreads();
        bf16x8 a[4], b[2];
#pragma unroll
        for (int i = 0; i < 4; ++i) a[i] = *(const bf16x8*)&As[(wm + i * 16 + l15) * 32 + quad * 8];
#pragma unroll
        for (int j = 0; j < 2; ++j) b[j] = *(const bf16x8*)&Bs[(wn + j * 16 + l15) * 32 + quad * 8];
#pragma unroll
        for (int i = 0; i < 4; ++i)
#pragma unroll
            for (int j = 0; j < 2; ++j)
                acc[i][j] = __builtin_amdgcn_mfma_f32_16x16x32_bf16(a[i], b[j], acc[i][j], 0, 0, 0);
    }

    const int h = n0 >> 6;                           // one head per block
#pragma unroll
    for (int i = 0; i < 4; ++i)
#pragma unroll
        for (int j = 0; j < 2; ++j) {
            const int d = wn + j * 16 + l15;         // 0..63 within head
            const float bv_ = bias[n0 + d];
            const int row0 = m0 + wm + i * 16 + quad * 4;   // b*2048 + t0
            const int b = row0 >> 11, t0 = row0 & 2047;
            const size_t obase = ((size_t)(b * 16 + h) * 2048 + t0) * 64 + d;
#pragma unroll
            for (int r = 0; r < 4; ++r) {
                float v = acc[i][j][r] + bv_;
                if (wsel < 2) v = phi(v);
                Ob[obase + (size_t)r * 64] = f2bf(v);
            }
        }
}

// ---------------- Kernel 2: per-chunk KV state: KV_c = K_c^T V_c, ksum_c ---
__global__ __launch_bounds__(256) void chunk_sums(
    const short* __restrict__ Kb, const short* __restrict__ Vb,
    short* __restrict__ KVsum, float* __restrict__ ksum)
{
    __shared__ short KT[64 * LDT];   // K^T : [d][t]  (swizzled cols)
    __shared__ short VT[64 * LDT];   // V^T : [e][t]  (swizzled cols)
    __shared__ float pS[256];
    const int c = blockIdx.x, bh = blockIdx.y;
    const int tid = threadIdx.x;
    const int w = tid >> 6, lane = tid & 63, l15 = lane & 15, quad = lane >> 4;
    const size_t tilebase = ((size_t)bh * 2048 + c * 64) * 64;

#pragma unroll
    for (int p = 0; p < 2; ++p) {
        const int t = (tid >> 3) + p * 32;
        const int e0 = (tid & 7) << 3;
        const size_t g = tilebase + (size_t)t * 64 + e0;   // contiguous 4KB span
        short8v kv = *(const short8v*)&Kb[g];
        short8v vv = *(const short8v*)&Vb[g];
#pragma unroll
        for (int jj = 0; jj < 8; ++jj) {
            KT[swz(e0 + jj, t)] = kv[jj];
            VT[swz(e0 + jj, t)] = vv[jj];
        }
    }
    __syncthreads();

    f32x4 acc[4] = {};
#pragma unroll
    for (int k0 = 0; k0 < 64; k0 += 32) {
        const int ra = w * 16 + l15;
        bf16x8 a = *(const bf16x8*)&KT[ra * LDT + ((k0 + quad * 8) ^ (ra & 56))];
#pragma unroll
        for (int tj = 0; tj < 4; ++tj) {
            const int rb = tj * 16 + l15;
            bf16x8 bfr = *(const bf16x8*)&VT[rb * LDT + ((k0 + quad * 8) ^ (rb & 56))];
            acc[tj] = __builtin_amdgcn_mfma_f32_16x16x32_bf16(a, bfr, acc[tj], 0, 0, 0);
        }
    }
    short* __restrict__ outp = KVsum + (((size_t)bh * 32) + c) * 4096;   // [d][e]
#pragma unroll
    for (int tj = 0; tj < 4; ++tj)
#pragma unroll
        for (int r = 0; r < 4; ++r)
            outp[(w * 16 + quad * 4 + r) * 64 + tj * 16 + l15] = f2bf(acc[tj][r]);

    {   // ksum partials: thread = (part, d)
        const int d = tid & 63, part = tid >> 6;
        short8v k1 = *(const short8v*)&KT[d * LDT + ((part * 16) ^ (d & 56))];
        short8v k2 = *(const short8v*)&KT[d * LDT + ((part * 16 + 8) ^ (d & 56))];
        float s = 0.f;
#pragma unroll
        for (int m = 0; m < 8; ++m) s += bf2f(k1[m]) + bf2f(k2[m]);
        pS[part * 64 + d] = s;
    }
    __syncthreads();
    if (tid < 64)
        ksum[(((size_t)bh * 32) + c) * 64 + tid] =
            pS[tid] + pS[tid + 64] + pS[tid + 128] + pS[tid + 192];
}

// ---------------- Kernel 3: exclusive prefix scan over 32 chunks -----------
__global__ __launch_bounds__(256) void scan_chunks(
    const short* __restrict__ KVsum, const float* __restrict__ ksum,
    short* __restrict__ KVpref, float* __restrict__ kpref)
{
    const int bh = blockIdx.y;
    const int o = blockIdx.x * 256 + threadIdx.x;     // 16 x 256 = 4096
    float run = 0.f;
    size_t base = (size_t)bh * 32 * 4096 + o;
    for (int cc = 0; cc < 32; ++cc) {
        KVpref[base] = f2bf(run);                     // exclusive
        run += bf2f(KVsum[base]);
        base += 4096;
    }
    if (blockIdx.x == 0 && threadIdx.x < 64) {
        float vals[32];
        const size_t kb = (size_t)bh * 32 * 64 + threadIdx.x;
#pragma unroll
        for (int cc = 0; cc < 32; ++cc) vals[cc] = ksum[kb + (size_t)cc * 64];
        float r2 = 0.f;
#pragma unroll
        for (int cc = 0; cc < 32; ++cc) { kpref[kb + (size_t)cc * 64] = r2; r2 += vals[cc]; }
    }
}

// ---------------- Kernel 4: per-chunk attention ----------------------------
__global__ __launch_bounds__(256) void attn_chunk(
    const short* __restrict__ Qb, const short* __restrict__ Kb,
    const short* __restrict__ Vb, const short* __restrict__ KVpref,
    const float* __restrict__ kpref, short* __restrict__ attnb)
{
    __shared__ short Qs[64 * LDT];
    __shared__ short KS[64 * LDT];   // K, then overwritten with masked S (straight)
    __shared__ short VT[64 * LDT];   // V^T  [e][t]  (swizzled)
    __shared__ short KVT[64 * LDT];  // KVpref^T [e][d]  (swizzled)
    const int c = blockIdx.x, bh = blockIdx.y;
    const int b = bh >> 4, h = bh & 15;
    const int tid = threadIdx.x;
    const int w = tid >> 6, lane = tid & 63, l15 = lane & 15, quad = lane >> 4;
    const size_t tilebase = ((size_t)bh * 2048 + c * 64) * 64;
    const short* __restrict__ KVc = KVpref + (((size_t)bh * 32) + c) * 4096;

#pragma unroll
    for (int p = 0; p < 2; ++p) {
        const int t = (tid >> 3) + p * 32;             // t for Q/K/V; d for KVpref
        const int e0 = (tid & 7) << 3;
        const size_t g = tilebase + (size_t)t * 64 + e0;  // contiguous 4KB span
        *(short8v*)&Qs[t * LDT + e0] = *(const short8v*)&Qb[g];
        *(short8v*)&KS[t * LDT + e0] = *(const short8v*)&Kb[g];
        short8v vv = *(const short8v*)&Vb[g];
        short8v pv = *(const short8v*)&KVc[t * 64 + e0];
#pragma unroll
        for (int jj = 0; jj < 8; ++jj) {
            VT[swz(e0 + jj, t)]  = vv[jj];
            KVT[swz(e0 + jj, t)] = pv[jj];
        }
    }
    __syncthreads();

    // ---- S = Q K^T ---------------------------------------------------------
    f32x4 sacc[4] = {};
#pragma unroll
    for (int k0 = 0; k0 < 64; k0 += 32) {
        bf16x8 a = *(const bf16x8*)&Qs[(w * 16 + l15) * LDT + k0 + quad * 8];
#pragma unroll
        for (int tj = 0; tj < 4; ++tj) {
            bf16x8 bfr = *(const bf16x8*)&KS[(tj * 16 + l15) * LDT + k0 + quad * 8];
            sacc[tj] = __builtin_amdgcn_mfma_f32_16x16x32_bf16(a, bfr, sacc[tj], 0, 0, 0);
        }
    }

    // ---- z via masked rowsum + q.kpref, 16-lane butterfly ------------------
    f32x4 kp4 = *(const f32x4*)&kpref[(((size_t)bh * 32) + c) * 64 + l15 * 4];
    float zinv[4];
#pragma unroll
    for (int r = 0; r < 4; ++r) {
        const int i = w * 16 + quad * 4 + r;
        float p = 0.f;
#pragma unroll
        for (int tj = 0; tj < 4; ++tj)
            if (tj * 16 + l15 <= i) p += sacc[tj][r];
        short4v q4 = *(const short4v*)&Qs[i * LDT + l15 * 4];
#pragma unroll
        for (int m = 0; m < 4; ++m) p += bf2f(q4[m]) * kp4[m];
        p += __shfl_xor(p, 1);
        p += __shfl_xor(p, 2);
        p += __shfl_xor(p, 4);
        p += __shfl_xor(p, 8);
        zinv[r] = 1.f / (p + 1e-6f);
    }

    __syncthreads();   // all waves done reading KS-as-K before overwrite
#pragma unroll
    for (int tj = 0; tj < 4; ++tj)
#pragma unroll
        for (int r = 0; r < 4; ++r) {
            const int i = w * 16 + quad * 4 + r;
            const int j = tj * 16 + l15;
            KS[i * LDT + j] = f2bf(j <= i ? sacc[tj][r] : 0.f);
        }
    // NO barrier: O-MFMA a1 reads KS rows [w*16, w*16+16) - wave-private.

    // ---- O = causal(S) V + Q KVpref ---------------------------------------
    f32x4 oacc[4] = {};
#pragma unroll
    for (int k0 = 0; k0 < 64; k0 += 32) {
        bf16x8 a1 = *(const bf16x8*)&KS[(w * 16 + l15) * LDT + k0 + quad * 8];
        bf16x8 a2 = *(const bf16x8*)&Qs[(w * 16 + l15) * LDT + k0 + quad * 8];
#pragma unroll
        for (int tj = 0; tj < 4; ++tj) {
            const int rb = tj * 16 + l15;
            bf16x8 b1 = *(const bf16x8*)&VT[rb * LDT + ((k0 + quad * 8) ^ (rb & 56))];
            bf16x8 b2 = *(const bf16x8*)&KVT[rb * LDT + ((k0 + quad * 8) ^ (rb & 56))];
            oacc[tj] = __builtin_amdgcn_mfma_f32_16x16x32_bf16(a1, b1, oacc[tj], 0, 0, 0);
            oacc[tj] = __builtin_amdgcn_mfma_f32_16x16x32_bf16(a2, b2, oacc[tj], 0, 0, 0);
        }
    }
    const size_t arowbase = (size_t)b * 2048 + c * 64;   // attnb stays [b,t][h,e]
#pragma unroll
    for (int tj = 0; tj < 4; ++tj)
#pragma unroll
        for (int r = 0; r < 4; ++r) {
            const int i = w * 16 + quad * 4 + r;
            const int e = tj * 16 + l15;
            attnb[(arowbase + i) * 1024 + h * 64 + e] = f2bf(oacc[tj][r] * zinv[r]);
        }
}

// ---------------- Kernel 5: output projection GEMM, 128x64 tile ------------
// Grid 32 x 16 = 512 blocks (2/CU).
__global__ __launch_bounds__(256) void gemm_out(
    const short* __restrict__ attnb, const short* __restrict__ Wob,
    const float* __restrict__ bo, float* __restrict__ outp)
{
    __shared__ short As[128 * 32];
    __shared__ short Bs[64 * 32];
    const int tid = threadIdx.x;
    const int bm = blockIdx.x, bn = blockIdx.y;      // 32 x 16
    const int m0 = bm << 7, n0 = bn << 6;
    const int wave = tid >> 6, lane = tid & 63;
    const int wm = (wave & 1) << 6, wn = (wave >> 1) << 5;
    const int l15 = lane & 15, quad = lane >> 4;

    const int lrow = lane >> 2, lcol = (lane & 3) << 3;
    const short* gp[3]; short* lp[3];
#pragma unroll
    for (int cc = 0; cc < 3; ++cc) {
        const int ch = wave * 3 + cc;
        if (ch < 8) {
            gp[cc] = attnb + (size_t)(m0 + ch * 16 + lrow) * 1024 + lcol;
            lp[cc] = &As[ch * 512];
        } else {
            gp[cc] = Wob + (size_t)(n0 + (ch - 8) * 16 + lrow) * 1024 + lcol;
            lp[cc] = &Bs[(ch - 8) * 512];
        }
    }

    f32x4 acc[4][2] = {};
    for (int k0 = 0; k0 < 1024; k0 += 32) {
        __syncthreads();
        gl_lds16(gp[0] + k0, lp[0]);
        gl_lds16(gp[1] + k0, lp[1]);
        gl_lds16(gp[2] + k0, lp[2]);
        __syncthreads();
        bf16x8 a[4], b[2];
#pragma unroll
        for (int i = 0; i < 4; ++i) a[i] = *(const bf16x8*)&As[(wm + i * 16 + l15) * 32 + quad * 8];
#pragma unroll
        for (int j = 0; j < 2; ++j) b[j] = *(const bf16x8*)&Bs[(wn + j * 16 + l15) * 32 + quad * 8];
#pragma unroll
        for (int i = 0; i < 4; ++i)
#pragma unroll
            for (int j = 0; j < 2; ++j)
                acc[i][j] = __builtin_amdgcn_mfma_f32_16x16x32_bf16(a[i], b[j], acc[i][j], 0, 0, 0);
    }

#pragma unroll
    for (int i = 0; i < 4; ++i)
#pragma unroll
        for (int j = 0; j < 2; ++j) {
            const int col = n0 + wn + j * 16 + l15;
            const float bv_ = bo[col];
#pragma unroll
            for (int r = 0; r < 4; ++r) {
                const int row = m0 + wm + i * 16 + quad * 4 + r;
                outp[(size_t)row * 1024 + col] = acc[i][j][r] + bv_;
            }
        }
}

// ---------------------------------------------------------------------------
extern "C" void kernel_launch(void* const* d_in, const int* in_sizes, int n_in,
                              void* d_out, int out_size, void* d_ws, size_t ws_size,
                              hipStream_t stream)
{
    const float* x  = (const float*)d_in[0];
    const float* Wq = (const float*)d_in[1];
    const float* bq = (const float*)d_in[2];
    const float* Wk = (const float*)d_in[3];
    const float* bk = (const float*)d_in[4];
    const float* Wv = (const float*)d_in[5];
    const float* bv = (const float*)d_in[6];
    const float* Wo = (const float*)d_in[7];
    const float* bo = (const float*)d_in[8];

    char* ws = (char*)d_ws;
    short* xb     = (short*)(ws + 0);          //  8 MB [4096][1024] bf16
    short* Wqb    = (short*)(ws + 8388608);    //  2 MB
    short* Wkb    = (short*)(ws + 10485760);   //  2 MB
    short* Wvb    = (short*)(ws + 12582912);   //  2 MB
    short* Wob    = (short*)(ws + 14680064);   //  2 MB
    short* Qb     = (short*)(ws + 16777216);   //  8 MB [bh*2048+t][64]
    short* Kb     = (short*)(ws + 25165824);   //  8 MB [bh*2048+t][64]
    short* Vb     = (short*)(ws + 33554432);   //  8 MB [bh*2048+t][64]
    short* KVsum  = (short*)(ws + 41943040);   //  8 MB [bh][c][d*64+e] bf16
    short* KVpref = (short*)(ws + 50331648);   //  8 MB bf16, same layout
    short* attnb  = (short*)(ws + 58720256);   //  8 MB [b,t][h*64+e]
    float* ksum   = (float*)(ws + 67108864);   // 256 KB
    float* kpref  = (float*)(ws + 67371008);   // 256 KB
    float* outp   = (float*)d_out;

    convert_bf16<<<4096, 256, 0, stream>>>(x, Wq, Wk, Wv, Wo, xb, Wqb, Wkb, Wvb, Wob);
    gemm_qkv   <<<dim3(32, 48), 256, 0, stream>>>(xb, Wqb, Wkb, Wvb, bq, bk, bv, Qb, Kb, Vb);
    chunk_sums <<<dim3(32, 32), 256, 0, stream>>>(Kb, Vb, KVsum, ksum);
    scan_chunks<<<dim3(16, 32), 256, 0, stream>>>(KVsum, ksum, KVpref, kpref);
    attn_chunk <<<dim3(32, 32), 256, 0, stream>>>(Qb, Kb, Vb, KVpref, kpref, attnb);
    gemm_out   <<<dim3(32, 16), 256, 0, stream>>>(attnb, Wob, bo, outp);
}

// Round 11
// 159.703 us; speedup vs baseline: 1.0812x; 1.0812x over previous
//
#include <hip/hip_runtime.h>

// ---------------------------------------------------------------------------
// Linear attention (causal, phi = elu+1), B=2 T=2048 H=16 dk=64 D=1024.
// r9 base (164.7 us) + gemm_out retiled 128x64 (512 blocks = 2/CU).
// r10 attribution: gemm_out at 128x128 was the ONLY 1-block/CU kernel (zero
// cross-block barrier overlap) -> retile wins there (-4us); gemm_qkv already
// had 3/CU at 128x128 -> its retile halved MFMA-per-barrier, +12us. Keep
// gemm_qkv at 128x128/BK=32.
// ---------------------------------------------------------------------------

typedef float  f32x4   __attribute__((ext_vector_type(4)));
typedef __bf16 bf16x8  __attribute__((ext_vector_type(8)));
typedef short  short8v __attribute__((ext_vector_type(8)));
typedef short  short4v __attribute__((ext_vector_type(4)));

static __device__ __forceinline__ short f2bf(float f) {
    unsigned u = __float_as_uint(f);
    u += 0x7FFFu + ((u >> 16) & 1u);          // RNE
    return (short)(u >> 16);
}
static __device__ __forceinline__ float bf2f(short s) {
    return __uint_as_float(((unsigned)(unsigned short)s) << 16);
}
static __device__ __forceinline__ float phi(float x) {   // elu(x)+1
    return x > 0.f ? x + 1.f : __expf(x);
}
static __device__ __forceinline__ void gl_lds16(const short* g, short* l) {
    __builtin_amdgcn_global_load_lds(
        (const __attribute__((address_space(1))) void*)g,
        (__attribute__((address_space(3))) void*)l, 16, 0, 0);
}

#define LDT 72   // 64x64 tile leading dim
static __device__ __forceinline__ int swz(int row, int col) {
    return row * LDT + (col ^ (row & 56));
}

// ---------------- Kernel 0: fp32 -> bf16 conversion ------------------------
__global__ __launch_bounds__(256) void convert_bf16(
    const float* __restrict__ x,  const float* __restrict__ Wq,
    const float* __restrict__ Wk, const float* __restrict__ Wv,
    const float* __restrict__ Wo,
    short* __restrict__ xb,  short* __restrict__ Wqb,
    short* __restrict__ Wkb, short* __restrict__ Wvb, short* __restrict__ Wob)
{
    const int blk = blockIdx.x;
    const float* src; short* dst; size_t base;
    if (blk < 2048)      { src = x;  dst = xb;  base = (size_t)blk * 2048; }
    else if (blk < 2560) { src = Wq; dst = Wqb; base = (size_t)(blk - 2048) * 2048; }
    else if (blk < 3072) { src = Wk; dst = Wkb; base = (size_t)(blk - 2560) * 2048; }
    else if (blk < 3584) { src = Wv; dst = Wvb; base = (size_t)(blk - 3072) * 2048; }
    else                 { src = Wo; dst = Wob; base = (size_t)(blk - 3584) * 2048; }
    const size_t o = base + (size_t)threadIdx.x * 8;
    f32x4 v0 = *(const f32x4*)&src[o];
    f32x4 v1 = *(const f32x4*)&src[o + 4];
    short8v s;
#pragma unroll
    for (int m = 0; m < 4; ++m) { s[m] = f2bf(v0[m]); s[m + 4] = f2bf(v1[m]); }
    *(short8v*)&dst[o] = s;
}

// ---------------- Kernel 1: fused QKV GEMM (m97, 128x128, BK=32) -----------
// Output layout: [(b*16+h)*2048 + t][64] bf16 for Q, K, V.
__global__ __launch_bounds__(256) void gemm_qkv(
    const short* __restrict__ xb,
    const short* __restrict__ Wqb, const short* __restrict__ Wkb,
    const short* __restrict__ Wvb,
    const float* __restrict__ bq, const float* __restrict__ bk,
    const float* __restrict__ bv,
    short* __restrict__ Qb, short* __restrict__ Kb, short* __restrict__ Vb)
{
    __shared__ short As[128 * 32];
    __shared__ short Bs[128 * 32];
    const int tid = threadIdx.x;
    const int bm = blockIdx.x, bn = blockIdx.y;      // 32 x 24
    const int wsel = bn >> 3;                        // 0=Q 1=K 2=V
    const int n0 = (bn & 7) << 7;
    const short* __restrict__ W    = (wsel == 0) ? Wqb : (wsel == 1) ? Wkb : Wvb;
    const float* __restrict__ bias = (wsel == 0) ? bq  : (wsel == 1) ? bk  : bv;
    short* __restrict__ Ob         = (wsel == 0) ? Qb  : (wsel == 1) ? Kb  : Vb;
    const int m0 = bm << 7;
    const int wave = tid >> 6, lane = tid & 63;
    const int wm = (wave & 1) << 6, wn = (wave >> 1) << 6;
    const int l15 = lane & 15, quad = lane >> 4;

    const int ch0 = wave * 2, ch1 = ch0 + 1;
    const int lrow = lane >> 2, lcol = (lane & 3) << 3;
    const short* ga0 = xb + (size_t)(m0 + ch0 * 16 + lrow) * 1024 + lcol;
    const short* ga1 = xb + (size_t)(m0 + ch1 * 16 + lrow) * 1024 + lcol;
    const short* gb0 = W  + (size_t)(n0 + ch0 * 16 + lrow) * 1024 + lcol;
    const short* gb1 = W  + (size_t)(n0 + ch1 * 16 + lrow) * 1024 + lcol;
    short* la0 = &As[ch0 * 512];
    short* la1 = &As[ch1 * 512];
    short* lb0 = &Bs[ch0 * 512];
    short* lb1 = &Bs[ch1 * 512];

    f32x4 acc[4][4] = {};
    for (int k0 = 0; k0 < 1024; k0 += 32) {
        __syncthreads();
        gl_lds16(ga0 + k0, la0);
        gl_lds16(ga1 + k0, la1);
        gl_lds16(gb0 + k0, lb0);
        gl_lds16(gb1 + k0, lb1);
        __syncthreads();
        bf16x8 a[4], b[4];
#pragma unroll
        for (int i = 0; i < 4; ++i) a[i] = *(const bf16x8*)&As[(wm + i * 16 + l15) * 32 + quad * 8];
#pragma unroll
        for (int j = 0; j < 4; ++j) b[j] = *(const bf16x8*)&Bs[(wn + j * 16 + l15) * 32 + quad * 8];
#pragma unroll
        for (int i = 0; i < 4; ++i)
#pragma unroll
            for (int j = 0; j < 4; ++j)
                acc[i][j] = __builtin_amdgcn_mfma_f32_16x16x32_bf16(a[i], b[j], acc[i][j], 0, 0, 0);
    }

#pragma unroll
    for (int i = 0; i < 4; ++i)
#pragma unroll
        for (int j = 0; j < 4; ++j) {
            const int col = n0 + wn + j * 16 + l15;     // h*64 + d
            const int h = col >> 6, d = col & 63;
            const float bv_ = bias[col];
            const int row0 = m0 + wm + i * 16 + quad * 4;   // b*2048 + t0
            const int b = row0 >> 11, t0 = row0 & 2047;
            const size_t obase = ((size_t)(b * 16 + h) * 2048 + t0) * 64 + d;
#pragma unroll
            for (int r = 0; r < 4; ++r) {
                float v = acc[i][j][r] + bv_;
                if (wsel < 2) v = phi(v);
                Ob[obase + (size_t)r * 64] = f2bf(v);
            }
        }
}

// ---------------- Kernel 2: per-chunk KV state: KV_c = K_c^T V_c, ksum_c ---
__global__ __launch_bounds__(256) void chunk_sums(
    const short* __restrict__ Kb, const short* __restrict__ Vb,
    short* __restrict__ KVsum, float* __restrict__ ksum)
{
    __shared__ short KT[64 * LDT];   // K^T : [d][t]  (swizzled cols)
    __shared__ short VT[64 * LDT];   // V^T : [e][t]  (swizzled cols)
    __shared__ float pS[256];
    const int c = blockIdx.x, bh = blockIdx.y;
    const int tid = threadIdx.x;
    const int w = tid >> 6, lane = tid & 63, l15 = lane & 15, quad = lane >> 4;
    const size_t tilebase = ((size_t)bh * 2048 + c * 64) * 64;

#pragma unroll
    for (int p = 0; p < 2; ++p) {
        const int t = (tid >> 3) + p * 32;
        const int e0 = (tid & 7) << 3;
        const size_t g = tilebase + (size_t)t * 64 + e0;   // contiguous 4KB span
        short8v kv = *(const short8v*)&Kb[g];
        short8v vv = *(const short8v*)&Vb[g];
#pragma unroll
        for (int jj = 0; jj < 8; ++jj) {
            KT[swz(e0 + jj, t)] = kv[jj];
            VT[swz(e0 + jj, t)] = vv[jj];
        }
    }
    __syncthreads();

    f32x4 acc[4] = {};
#pragma unroll
    for (int k0 = 0; k0 < 64; k0 += 32) {
        const int ra = w * 16 + l15;
        bf16x8 a = *(const bf16x8*)&KT[ra * LDT + ((k0 + quad * 8) ^ (ra & 56))];
#pragma unroll
        for (int tj = 0; tj < 4; ++tj) {
            const int rb = tj * 16 + l15;
            bf16x8 bfr = *(const bf16x8*)&VT[rb * LDT + ((k0 + quad * 8) ^ (rb & 56))];
            acc[tj] = __builtin_amdgcn_mfma_f32_16x16x32_bf16(a, bfr, acc[tj], 0, 0, 0);
        }
    }
    short* __restrict__ outp = KVsum + (((size_t)bh * 32) + c) * 4096;   // [d][e]
#pragma unroll
    for (int tj = 0; tj < 4; ++tj)
#pragma unroll
        for (int r = 0; r < 4; ++r)
            outp[(w * 16 + quad * 4 + r) * 64 + tj * 16 + l15] = f2bf(acc[tj][r]);

    {   // ksum partials: thread = (part, d)
        const int d = tid & 63, part = tid >> 6;
        short8v k1 = *(const short8v*)&KT[d * LDT + ((part * 16) ^ (d & 56))];
        short8v k2 = *(const short8v*)&KT[d * LDT + ((part * 16 + 8) ^ (d & 56))];
        float s = 0.f;
#pragma unroll
        for (int m = 0; m < 8; ++m) s += bf2f(k1[m]) + bf2f(k2[m]);
        pS[part * 64 + d] = s;
    }
    __syncthreads();
    if (tid < 64)
        ksum[(((size_t)bh * 32) + c) * 64 + tid] =
            pS[tid] + pS[tid + 64] + pS[tid + 128] + pS[tid + 192];
}

// ---------------- Kernel 3: exclusive prefix scan over 32 chunks -----------
__global__ __launch_bounds__(256) void scan_chunks(
    const short* __restrict__ KVsum, const float* __restrict__ ksum,
    short* __restrict__ KVpref, float* __restrict__ kpref)
{
    const int bh = blockIdx.y;
    const int o = blockIdx.x * 256 + threadIdx.x;     // 16 x 256 = 4096
    float run = 0.f;
    size_t base = (size_t)bh * 32 * 4096 + o;
    for (int cc = 0; cc < 32; ++cc) {
        KVpref[base] = f2bf(run);                     // exclusive
        run += bf2f(KVsum[base]);
        base += 4096;
    }
    if (blockIdx.x == 0 && threadIdx.x < 64) {
        float vals[32];
        const size_t kb = (size_t)bh * 32 * 64 + threadIdx.x;
#pragma unroll
        for (int cc = 0; cc < 32; ++cc) vals[cc] = ksum[kb + (size_t)cc * 64];
        float r2 = 0.f;
#pragma unroll
        for (int cc = 0; cc < 32; ++cc) { kpref[kb + (size_t)cc * 64] = r2; r2 += vals[cc]; }
    }
}

// ---------------- Kernel 4: per-chunk attention ----------------------------
__global__ __launch_bounds__(256) void attn_chunk(
    const short* __restrict__ Qb, const short* __restrict__ Kb,
    const short* __restrict__ Vb, const short* __restrict__ KVpref,
    const float* __restrict__ kpref, short* __restrict__ attnb)
{
    __shared__ short Qs[64 * LDT];
    __shared__ short KS[64 * LDT];   // K, then overwritten with masked S (straight)
    __shared__ short VT[64 * LDT];   // V^T  [e][t]  (swizzled)
    __shared__ short KVT[64 * LDT];  // KVpref^T [e][d]  (swizzled)
    const int c = blockIdx.x, bh = blockIdx.y;
    const int b = bh >> 4, h = bh & 15;
    const int tid = threadIdx.x;
    const int w = tid >> 6, lane = tid & 63, l15 = lane & 15, quad = lane >> 4;
    const size_t tilebase = ((size_t)bh * 2048 + c * 64) * 64;
    const short* __restrict__ KVc = KVpref + (((size_t)bh * 32) + c) * 4096;

#pragma unroll
    for (int p = 0; p < 2; ++p) {
        const int t = (tid >> 3) + p * 32;             // t for Q/K/V; d for KVpref
        const int e0 = (tid & 7) << 3;
        const size_t g = tilebase + (size_t)t * 64 + e0;  // contiguous 4KB span
        *(short8v*)&Qs[t * LDT + e0] = *(const short8v*)&Qb[g];
        *(short8v*)&KS[t * LDT + e0] = *(const short8v*)&Kb[g];
        short8v vv = *(const short8v*)&Vb[g];
        short8v pv = *(const short8v*)&KVc[t * 64 + e0];
#pragma unroll
        for (int jj = 0; jj < 8; ++jj) {
            VT[swz(e0 + jj, t)]  = vv[jj];
            KVT[swz(e0 + jj, t)] = pv[jj];
        }
    }
    __syncthreads();

    // ---- S = Q K^T ---------------------------------------------------------
    f32x4 sacc[4] = {};
#pragma unroll
    for (int k0 = 0; k0 < 64; k0 += 32) {
        bf16x8 a = *(const bf16x8*)&Qs[(w * 16 + l15) * LDT + k0 + quad * 8];
#pragma unroll
        for (int tj = 0; tj < 4; ++tj) {
            bf16x8 bfr = *(const bf16x8*)&KS[(tj * 16 + l15) * LDT + k0 + quad * 8];
            sacc[tj] = __builtin_amdgcn_mfma_f32_16x16x32_bf16(a, bfr, sacc[tj], 0, 0, 0);
        }
    }

    // ---- z via masked rowsum + q.kpref, 16-lane butterfly ------------------
    f32x4 kp4 = *(const f32x4*)&kpref[(((size_t)bh * 32) + c) * 64 + l15 * 4];
    float zinv[4];
#pragma unroll
    for (int r = 0; r < 4; ++r) {
        const int i = w * 16 + quad * 4 + r;
        float p = 0.f;
#pragma unroll
        for (int tj = 0; tj < 4; ++tj)
            if (tj * 16 + l15 <= i) p += sacc[tj][r];
        short4v q4 = *(const short4v*)&Qs[i * LDT + l15 * 4];
#pragma unroll
        for (int m = 0; m < 4; ++m) p += bf2f(q4[m]) * kp4[m];
        p += __shfl_xor(p, 1);
        p += __shfl_xor(p, 2);
        p += __shfl_xor(p, 4);
        p += __shfl_xor(p, 8);
        zinv[r] = 1.f / (p + 1e-6f);
    }

    __syncthreads();   // all waves done reading KS-as-K before overwrite
#pragma unroll
    for (int tj = 0; tj < 4; ++tj)
#pragma unroll
        for (int r = 0; r < 4; ++r) {
            const int i = w * 16 + quad * 4 + r;
            const int j = tj * 16 + l15;
            KS[i * LDT + j] = f2bf(j <= i ? sacc[tj][r] : 0.f);
        }
    // NO barrier: O-MFMA a1 reads KS rows [w*16, w*16+16) - wave-private.

    // ---- O = causal(S) V + Q KVpref ---------------------------------------
    f32x4 oacc[4] = {};
#pragma unroll
    for (int k0 = 0; k0 < 64; k0 += 32) {
        bf16x8 a1 = *(const bf16x8*)&KS[(w * 16 + l15) * LDT + k0 + quad * 8];
        bf16x8 a2 = *(const bf16x8*)&Qs[(w * 16 + l15) * LDT + k0 + quad * 8];
#pragma unroll
        for (int tj = 0; tj < 4; ++tj) {
            const int rb = tj * 16 + l15;
            bf16x8 b1 = *(const bf16x8*)&VT[rb * LDT + ((k0 + quad * 8) ^ (rb & 56))];
            bf16x8 b2 = *(const bf16x8*)&KVT[rb * LDT + ((k0 + quad * 8) ^ (rb & 56))];
            oacc[tj] = __builtin_amdgcn_mfma_f32_16x16x32_bf16(a1, b1, oacc[tj], 0, 0, 0);
            oacc[tj] = __builtin_amdgcn_mfma_f32_16x16x32_bf16(a2, b2, oacc[tj], 0, 0, 0);
        }
    }
    const size_t arowbase = (size_t)b * 2048 + c * 64;   // attnb stays [b,t][h,e]
#pragma unroll
    for (int tj = 0; tj < 4; ++tj)
#pragma unroll
        for (int r = 0; r < 4; ++r) {
            const int i = w * 16 + quad * 4 + r;
            const int e = tj * 16 + l15;
            attnb[(arowbase + i) * 1024 + h * 64 + e] = f2bf(oacc[tj][r] * zinv[r]);
        }
}

// ---------------- Kernel 5: output projection GEMM, 128x64 tile ------------
// Grid 32 x 16 = 512 blocks (2/CU): gemm_out was the only 1/CU kernel.
__global__ __launch_bounds__(256) void gemm_out(
    const short* __restrict__ attnb, const short* __restrict__ Wob,
    const float* __restrict__ bo, float* __restrict__ outp)
{
    __shared__ short As[128 * 32];
    __shared__ short Bs[64 * 32];
    const int tid = threadIdx.x;
    const int bm = blockIdx.x, bn = blockIdx.y;      // 32 x 16
    const int m0 = bm << 7, n0 = bn << 6;
    const int wave = tid >> 6, lane = tid & 63;
    const int wm = (wave & 1) << 6, wn = (wave >> 1) << 5;
    const int l15 = lane & 15, quad = lane >> 4;

    const int lrow = lane >> 2, lcol = (lane & 3) << 3;
    const short* gp[3]; short* lp[3];
#pragma unroll
    for (int cc = 0; cc < 3; ++cc) {
        const int ch = wave * 3 + cc;
        if (ch < 8) {
            gp[cc] = attnb + (size_t)(m0 + ch * 16 + lrow) * 1024 + lcol;
            lp[cc] = &As[ch * 512];
        } else {
            gp[cc] = Wob + (size_t)(n0 + (ch - 8) * 16 + lrow) * 1024 + lcol;
            lp[cc] = &Bs[(ch - 8) * 512];
        }
    }

    f32x4 acc[4][2] = {};
    for (int k0 = 0; k0 < 1024; k0 += 32) {
        __syncthreads();
        gl_lds16(gp[0] + k0, lp[0]);
        gl_lds16(gp[1] + k0, lp[1]);
        gl_lds16(gp[2] + k0, lp[2]);
        __syncthreads();
        bf16x8 a[4], b[2];
#pragma unroll
        for (int i = 0; i < 4; ++i) a[i] = *(const bf16x8*)&As[(wm + i * 16 + l15) * 32 + quad * 8];
#pragma unroll
        for (int j = 0; j < 2; ++j) b[j] = *(const bf16x8*)&Bs[(wn + j * 16 + l15) * 32 + quad * 8];
#pragma unroll
        for (int i = 0; i < 4; ++i)
#pragma unroll
            for (int j = 0; j < 2; ++j)
                acc[i][j] = __builtin_amdgcn_mfma_f32_16x16x32_bf16(a[i], b[j], acc[i][j], 0, 0, 0);
    }

#pragma unroll
    for (int i = 0; i < 4; ++i)
#pragma unroll
        for (int j = 0; j < 2; ++j) {
            const int col = n0 + wn + j * 16 + l15;
            const float bv_ = bo[col];
#pragma unroll
            for (int r = 0; r < 4; ++r) {
                const int row = m0 + wm + i * 16 + quad * 4 + r;
                outp[(size_t)row * 1024 + col] = acc[i][j][r] + bv_;
            }
        }
}

// ---------------------------------------------------------------------------
extern "C" void kernel_launch(void* const* d_in, const int* in_sizes, int n_in,
                              void* d_out, int out_size, void* d_ws, size_t ws_size,
                              hipStream_t stream)
{
    const float* x  = (const float*)d_in[0];
    const float* Wq = (const float*)d_in[1];
    const float* bq = (const float*)d_in[2];
    const float* Wk = (const float*)d_in[3];
    const float* bk = (const float*)d_in[4];
    const float* Wv = (const float*)d_in[5];
    const float* bv = (const float*)d_in[6];
    const float* Wo = (const float*)d_in[7];
    const float* bo = (const float*)d_in[8];

    char* ws = (char*)d_ws;
    short* xb     = (short*)(ws + 0);          //  8 MB [4096][1024] bf16
    short* Wqb    = (short*)(ws + 8388608);    //  2 MB
    short* Wkb    = (short*)(ws + 10485760);   //  2 MB
    short* Wvb    = (short*)(ws + 12582912);   //  2 MB
    short* Wob    = (short*)(ws + 14680064);   //  2 MB
    short* Qb     = (short*)(ws + 16777216);   //  8 MB [bh*2048+t][64]
    short* Kb     = (short*)(ws + 25165824);   //  8 MB [bh*2048+t][64]
    short* Vb     = (short*)(ws + 33554432);   //  8 MB [bh*2048+t][64]
    short* KVsum  = (short*)(ws + 41943040);   //  8 MB [bh][c][d*64+e] bf16
    short* KVpref = (short*)(ws + 50331648);   //  8 MB bf16, same layout
    short* attnb  = (short*)(ws + 58720256);   //  8 MB [b,t][h*64+e]
    float* ksum   = (float*)(ws + 67108864);   // 256 KB
    float* kpref  = (float*)(ws + 67371008);   // 256 KB
    float* outp   = (float*)d_out;

    convert_bf16<<<4096, 256, 0, stream>>>(x, Wq, Wk, Wv, Wo, xb, Wqb, Wkb, Wvb, Wob);
    gemm_qkv   <<<dim3(32, 24), 256, 0, stream>>>(xb, Wqb, Wkb, Wvb, bq, bk, bv, Qb, Kb, Vb);
    chunk_sums <<<dim3(32, 32), 256, 0, stream>>>(Kb, Vb, KVsum, ksum);
    scan_chunks<<<dim3(16, 32), 256, 0, stream>>>(KVsum, ksum, KVpref, kpref);
    attn_chunk <<<dim3(32, 32), 256, 0, stream>>>(Qb, Kb, Vb, KVpref, kpref, attnb);
    gemm_out   <<<dim3(32, 16), 256, 0, stream>>>(attnb, Wob, bo, outp);
}